// Round 1
// baseline (1175.231 us; speedup 1.0000x reference)
//
#include <hip/hip_runtime.h>
#include <hip/hip_bf16.h>

#define NUM_NODES 50000
#define NUM_EDGES 800000
#define IN_DIM 256
#define OUT_DIM 256
#define NUM_HEADS 8
#define HEAD_DIM 32

// ---------- helpers ----------
__device__ __forceinline__ unsigned float_to_key(float f) {
    int i = __float_as_int(f);
    return (i >= 0) ? ((unsigned)i | 0x80000000u) : ~(unsigned)i;
}
__device__ __forceinline__ float key_to_float(unsigned u) {
    unsigned b = (u & 0x80000000u) ? (u & 0x7fffffffu) : ~u;
    return __int_as_float((int)b);
}

// ---------- GEMM: C[M, Ncols] = A[M,256] @ W + b ----------
// Weights grouped per 256 output cols: g = colbase>>8 selects W0/W1/W2.
__global__ __launch_bounds__(256) void gemm_kernel(
    const float* __restrict__ A, int M, int Ncols,
    const float* __restrict__ W0, const float* __restrict__ W1, const float* __restrict__ W2,
    const float* __restrict__ b0, const float* __restrict__ b1, const float* __restrict__ b2,
    float* __restrict__ C)
{
    const int K = 256;
    __shared__ float As[16][132];
    __shared__ float Ws[16][132];
    int tid = threadIdx.x;
    int colbase = blockIdx.x * 128;
    int rowbase = blockIdx.y * 128;
    int g = colbase >> 8;
    int lb = colbase & 255;
    const float* W = (g == 0) ? W0 : (g == 1) ? W1 : W2;
    const float* bias = (g == 0) ? b0 : (g == 1) ? b1 : b2;
    int tx = tid & 15, ty = tid >> 4;

    float acc[8][8];
#pragma unroll
    for (int i = 0; i < 8; i++)
#pragma unroll
        for (int j = 0; j < 8; j++) acc[i][j] = 0.f;

    int ar = tid >> 2;        // 0..63
    int ak = (tid & 3) * 4;   // 0,4,8,12
    int wk = tid >> 4;        // 0..15
    int wc = (tid & 15) * 8;  // 0..120

    for (int kk = 0; kk < K; kk += 16) {
        // A tile: 128 rows x 16 k
#pragma unroll
        for (int rr = 0; rr < 2; rr++) {
            int r = ar + rr * 64;
            int grow = rowbase + r;
            float4 av = make_float4(0.f, 0.f, 0.f, 0.f);
            if (grow < M) av = *(const float4*)(A + (size_t)grow * K + kk + ak);
            As[ak + 0][r] = av.x; As[ak + 1][r] = av.y;
            As[ak + 2][r] = av.z; As[ak + 3][r] = av.w;
        }
        // W tile: 16 k x 128 cols
        {
            const float* wp = W + (size_t)(kk + wk) * 256 + lb + wc;
            float4 w0 = *(const float4*)wp;
            float4 w1 = *(const float4*)(wp + 4);
            *(float4*)&Ws[wk][wc] = w0;
            *(float4*)&Ws[wk][wc + 4] = w1;
        }
        __syncthreads();
#pragma unroll
        for (int k = 0; k < 16; k++) {
            float a[8], b[8];
#pragma unroll
            for (int i = 0; i < 8; i++) a[i] = As[k][ty * 8 + i];
#pragma unroll
            for (int j = 0; j < 8; j++) b[j] = Ws[k][tx * 8 + j];
#pragma unroll
            for (int i = 0; i < 8; i++)
#pragma unroll
                for (int j = 0; j < 8; j++) acc[i][j] += a[i] * b[j];
        }
        __syncthreads();
    }
#pragma unroll
    for (int i = 0; i < 8; i++) {
        int row = rowbase + ty * 8 + i;
        if (row >= M) continue;
        float* cp = C + (size_t)row * Ncols + colbase + tx * 8;
#pragma unroll
        for (int j = 0; j < 8; j++) cp[j] = acc[i][j] + bias[lb + tx * 8 + j];
    }
}

// ---------- scores + per-head max partials ----------
__global__ __launch_bounds__(256) void score_kernel(
    const float* __restrict__ qkv, const int* __restrict__ src_idx, const int* __restrict__ dst_idx,
    const float* __restrict__ edge_time, const float* __restrict__ node_time,
    const float* __restrict__ Wt, const float* __restrict__ bt,
    float* __restrict__ scores, unsigned* __restrict__ partialmax)
{
    __shared__ unsigned smax[8];
    int tid = threadIdx.x;
    if (tid < 8) smax[tid] = 0u;
    __syncthreads();
    const int total = NUM_EDGES * 8;
    int t0 = blockIdx.x * 256 + tid;
    int stride = gridDim.x * 256;   // multiple of 8 -> h constant per thread
    int h = t0 & 7;
    float wt0 = Wt[h], wt1 = Wt[8 + h], btv = bt[h];
    unsigned mykey = 0u;
    for (int t = t0; t < total; t += stride) {
        int e = t >> 3;
        int s = src_idx[e], d = dst_idx[e];
        const float4* qp = (const float4*)(qkv + (size_t)d * 768 + h * 32);
        const float4* kp = (const float4*)(qkv + (size_t)s * 768 + 256 + h * 32);
        float dotv = 0.f;
#pragma unroll
        for (int i = 0; i < 8; i++) {
            float4 a = qp[i], b = kp[i];
            dotv += a.x * b.x + a.y * b.y + a.z * b.z + a.w * b.w;
        }
        float td = edge_time[e] - node_time[d];
        float tf0 = (td > 0.f) ? 1.f : ((td < 0.f) ? -1.f : 0.f);
        float tf1 = log1pf(fabsf(td) * (1.f / 3600.f));
        float sc = dotv * 0.17677669529663687f + (tf0 * wt0 + tf1 * wt1 + btv);
        scores[t] = sc;
        unsigned k = float_to_key(sc);
        mykey = (k > mykey) ? k : mykey;
    }
    atomicMax(&smax[h], mykey);
    __syncthreads();
    if (tid < 8) partialmax[blockIdx.x * 8 + tid] = smax[tid];
}

__global__ __launch_bounds__(256) void reduce_max_kernel(
    const unsigned* __restrict__ partialmax, float* __restrict__ headmax)
{
    int tid = threadIdx.x;
    int h = tid >> 5, lane = tid & 31;
    unsigned m = 0u;
    for (int i = lane; i < 1024; i += 32) {
        unsigned v = partialmax[i * 8 + h];
        m = (v > m) ? v : m;
    }
    for (int off = 16; off > 0; off >>= 1) {
        unsigned o = __shfl_down(m, off, 32);
        m = (o > m) ? o : m;
    }
    if (lane == 0) headmax[h] = key_to_float(m);
}

// ---------- p = exp(s - max), per-head sum partials ----------
__global__ __launch_bounds__(256) void exp_kernel(
    float* __restrict__ scores, const float* __restrict__ headmax,
    float* __restrict__ partialsum)
{
    __shared__ float ssum[8];
    int tid = threadIdx.x;
    if (tid < 8) ssum[tid] = 0.f;
    __syncthreads();
    const int total = NUM_EDGES * 8;
    int t0 = blockIdx.x * 256 + tid;
    int stride = gridDim.x * 256;
    int h = t0 & 7;
    float m = headmax[h];
    float mysum = 0.f;
    for (int t = t0; t < total; t += stride) {
        float p = expf(scores[t] - m);
        scores[t] = p;
        mysum += p;
    }
    atomicAdd(&ssum[h], mysum);
    __syncthreads();
    if (tid < 8) partialsum[blockIdx.x * 8 + tid] = ssum[tid];
}

__global__ __launch_bounds__(256) void reduce_sum_kernel(
    const float* __restrict__ partialsum, float* __restrict__ headinv)
{
    int tid = threadIdx.x;
    int h = tid >> 5, lane = tid & 31;
    float s = 0.f;
    for (int i = lane; i < 1024; i += 32) s += partialsum[i * 8 + h];
    for (int off = 16; off > 0; off >>= 1) s += __shfl_down(s, off, 32);
    if (lane == 0) headinv[h] = 1.f / s;
}

// ---------- CSR build ----------
__global__ __launch_bounds__(256) void deg_kernel(const int* __restrict__ dst_idx, int* __restrict__ deg) {
    int e = blockIdx.x * 256 + threadIdx.x;
    if (e < NUM_EDGES) atomicAdd(&deg[dst_idx[e]], 1);
}

__global__ __launch_bounds__(1024) void scan_kernel(
    const int* __restrict__ deg, int* __restrict__ offs, int* __restrict__ cursor)
{
    __shared__ int buf[1024];
    __shared__ int carry;
    int tid = threadIdx.x;
    if (tid == 0) carry = 0;
    __syncthreads();
    for (int base = 0; base < NUM_NODES; base += 1024) {
        int i = base + tid;
        int v = (i < NUM_NODES) ? deg[i] : 0;
        buf[tid] = v;
        __syncthreads();
        for (int off = 1; off < 1024; off <<= 1) {
            int t = (tid >= off) ? buf[tid - off] : 0;
            __syncthreads();
            buf[tid] += t;
            __syncthreads();
        }
        int excl = buf[tid] - v;
        if (i < NUM_NODES) { offs[i] = carry + excl; cursor[i] = carry + excl; }
        __syncthreads();
        if (tid == 0) carry += buf[1023];
        __syncthreads();
    }
    if (tid == 0) offs[NUM_NODES] = carry;
}

__global__ __launch_bounds__(256) void fill_kernel(
    const int* __restrict__ dst_idx, int* __restrict__ cursor, int* __restrict__ edge_of)
{
    int e = blockIdx.x * 256 + threadIdx.x;
    if (e < NUM_EDGES) {
        int pos = atomicAdd(&cursor[dst_idx[e]], 1);
        edge_of[pos] = e;
    }
}

// ---------- aggregation: agg[n, h*32+d] = sum_e alpha[e,h]*v[src,h,d] ----------
__global__ __launch_bounds__(256) void aggregate_kernel(
    const float* __restrict__ qkv, const float* __restrict__ p,
    const int* __restrict__ src_idx, const int* __restrict__ offs,
    const int* __restrict__ edge_of, const float* __restrict__ headinv,
    float* __restrict__ agg)
{
    __shared__ int se[64];
    __shared__ int ssrc[64];
    int n = blockIdx.x;
    int tid = threadIdx.x;
    int h = tid >> 5;
    int start = offs[n], end = offs[n + 1];
    float acc = 0.f;
    for (int cb = start; cb < end; cb += 64) {
        int m = min(64, end - cb);
        __syncthreads();
        if (tid < m) { int e = edge_of[cb + tid]; se[tid] = e; ssrc[tid] = src_idx[e]; }
        __syncthreads();
        for (int j = 0; j < m; j++) {
            int e = se[j], s = ssrc[j];
            float pv = p[(size_t)e * 8 + h];
            acc += pv * qkv[(size_t)s * 768 + 512 + tid];
        }
    }
    agg[(size_t)n * 256 + tid] = acc * headinv[h];
}

extern "C" void kernel_launch(void* const* d_in, const int* in_sizes, int n_in,
                              void* d_out, int out_size, void* d_ws, size_t ws_size,
                              hipStream_t stream) {
    const float* x = (const float*)d_in[0];
    const int* ei = (const int*)d_in[1];
    const int* src_idx = ei;
    const int* dst_idx = ei + NUM_EDGES;
    const float* edge_time = (const float*)d_in[2];
    const float* node_time = (const float*)d_in[3];
    const float* Wq = (const float*)d_in[4];  const float* bq = (const float*)d_in[5];
    const float* Wk = (const float*)d_in[6];  const float* bk = (const float*)d_in[7];
    const float* Wv = (const float*)d_in[8];  const float* bv = (const float*)d_in[9];
    const float* Wt = (const float*)d_in[10]; const float* bt = (const float*)d_in[11];
    const float* Wo = (const float*)d_in[12]; const float* bo = (const float*)d_in[13];
    float* out = (float*)d_out;

    char* w = (char*)d_ws;
    float* qkv = (float*)w;        w += (size_t)NUM_NODES * 768 * 4;
    float* pbuf = (float*)w;       w += (size_t)NUM_EDGES * 8 * 4;
    float* agg = (float*)w;        w += (size_t)NUM_NODES * 256 * 4;
    unsigned* partialmax = (unsigned*)w; w += 1024 * 8 * 4;
    float* partialsum = (float*)w; w += 1024 * 8 * 4;
    float* headmax = (float*)w;    w += 8 * 4;
    float* headinv = (float*)w;    w += 8 * 4;
    int* deg = (int*)w;            w += (size_t)NUM_NODES * 4;
    int* offs = (int*)w;           w += (size_t)(NUM_NODES + 1) * 4;
    int* cursor = (int*)w;         w += (size_t)NUM_NODES * 4;
    int* edge_of = (int*)w;        w += (size_t)NUM_EDGES * 4;

    hipMemsetAsync(deg, 0, (size_t)NUM_NODES * 4, stream);

    // QKV projection: [N,256] @ [256,768]
    dim3 gq(768 / 128, (NUM_NODES + 127) / 128);
    gemm_kernel<<<gq, 256, 0, stream>>>(x, NUM_NODES, 768, Wq, Wk, Wv, bq, bk, bv, qkv);

    // scores + max partials
    score_kernel<<<1024, 256, 0, stream>>>(qkv, src_idx, dst_idx, edge_time, node_time,
                                           Wt, bt, pbuf, partialmax);
    reduce_max_kernel<<<1, 256, 0, stream>>>(partialmax, headmax);

    // exp + sum partials
    exp_kernel<<<1024, 256, 0, stream>>>(pbuf, headmax, partialsum);
    reduce_sum_kernel<<<1, 256, 0, stream>>>(partialsum, headinv);

    // CSR by dst
    deg_kernel<<<(NUM_EDGES + 255) / 256, 256, 0, stream>>>(dst_idx, deg);
    scan_kernel<<<1, 1024, 0, stream>>>(deg, offs, cursor);
    fill_kernel<<<(NUM_EDGES + 255) / 256, 256, 0, stream>>>(dst_idx, cursor, edge_of);

    // aggregate messages
    aggregate_kernel<<<NUM_NODES, 256, 0, stream>>>(qkv, pbuf, src_idx, offs, edge_of,
                                                    headinv, agg);

    // output projection: [N,256] @ [256,256]
    dim3 go(256 / 128, (NUM_NODES + 127) / 128);
    gemm_kernel<<<go, 256, 0, stream>>>(agg, NUM_NODES, 256, Wo, Wo, Wo, bo, bo, bo, out);
}

// Round 2
// 708.901 us; speedup vs baseline: 1.6578x; 1.6578x over previous
//
#include <hip/hip_runtime.h>
#include <hip/hip_bf16.h>

#define NUM_NODES 50000
#define NUM_EDGES 800000
#define NUM_HEADS 8
#define HEAD_DIM 32

typedef unsigned short ushort8 __attribute__((ext_vector_type(8)));

__device__ __forceinline__ unsigned float_to_key(float f) {
    int i = __float_as_int(f);
    return (i >= 0) ? ((unsigned)i | 0x80000000u) : ~(unsigned)i;
}
__device__ __forceinline__ float key_to_float(unsigned u) {
    unsigned b = (u & 0x80000000u) ? (u & 0x7fffffffu) : ~u;
    return __int_as_float((int)b);
}
__device__ __forceinline__ float bf2f(unsigned short u) {
    return __uint_as_float(((unsigned)u) << 16);
}

// ---------- CSR build ----------
__global__ __launch_bounds__(256) void deg_kernel(const int* __restrict__ dst_idx, int* __restrict__ deg) {
    int e = blockIdx.x * 256 + threadIdx.x;
    if (e < NUM_EDGES) atomicAdd(&deg[dst_idx[e]], 1);
}

__global__ __launch_bounds__(1024) void scan_kernel(
    const int* __restrict__ deg, int* __restrict__ offs, int* __restrict__ cursor)
{
    __shared__ int buf[1024];
    __shared__ int carry;
    int tid = threadIdx.x;
    if (tid == 0) carry = 0;
    __syncthreads();
    for (int base = 0; base < NUM_NODES; base += 1024) {
        int i = base + tid;
        int v = (i < NUM_NODES) ? deg[i] : 0;
        buf[tid] = v;
        __syncthreads();
        for (int off = 1; off < 1024; off <<= 1) {
            int t = (tid >= off) ? buf[tid - off] : 0;
            __syncthreads();
            buf[tid] += t;
            __syncthreads();
        }
        int excl = buf[tid] - v;
        if (i < NUM_NODES) { offs[i] = carry + excl; cursor[i] = carry + excl; }
        __syncthreads();
        if (tid == 0) carry += buf[1023];
        __syncthreads();
    }
    if (tid == 0) offs[NUM_NODES] = carry;
}

// fill CSR-ordered gathered edge arrays
__global__ __launch_bounds__(256) void fill2_kernel(
    const int* __restrict__ src_idx, const int* __restrict__ dst_idx,
    const float* __restrict__ edge_time, int* __restrict__ cursor,
    int* __restrict__ src_s, int* __restrict__ dst_s, float* __restrict__ et_s)
{
    int e = blockIdx.x * 256 + threadIdx.x;
    if (e < NUM_EDGES) {
        int d = dst_idx[e];
        int pos = atomicAdd(&cursor[d], 1);
        src_s[pos] = src_idx[e];
        dst_s[pos] = d;
        et_s[pos] = edge_time[e];
    }
}

// ---------- QKV GEMM: fp32 compute, bf16 outputs q/k/v [N,256] ----------
__global__ __launch_bounds__(256) void gemm_qkv_kernel(
    const float* __restrict__ A, int M,
    const float* __restrict__ W0, const float* __restrict__ W1, const float* __restrict__ W2,
    const float* __restrict__ b0, const float* __restrict__ b1, const float* __restrict__ b2,
    __hip_bfloat16* __restrict__ O0, __hip_bfloat16* __restrict__ O1, __hip_bfloat16* __restrict__ O2)
{
    const int K = 256;
    __shared__ float As[16][132];
    __shared__ float Ws[16][132];
    int tid = threadIdx.x;
    int colbase = blockIdx.x * 128;   // 0..640
    int rowbase = blockIdx.y * 128;
    int g = colbase >> 8;
    int lb = colbase & 255;
    const float* W = (g == 0) ? W0 : (g == 1) ? W1 : W2;
    const float* bias = (g == 0) ? b0 : (g == 1) ? b1 : b2;
    __hip_bfloat16* O = (g == 0) ? O0 : (g == 1) ? O1 : O2;
    int tx = tid & 15, ty = tid >> 4;

    float acc[8][8];
#pragma unroll
    for (int i = 0; i < 8; i++)
#pragma unroll
        for (int j = 0; j < 8; j++) acc[i][j] = 0.f;

    int ar = tid >> 2;
    int ak = (tid & 3) * 4;
    int wk = tid >> 4;
    int wc = (tid & 15) * 8;

    for (int kk = 0; kk < K; kk += 16) {
#pragma unroll
        for (int rr = 0; rr < 2; rr++) {
            int r = ar + rr * 64;
            int grow = rowbase + r;
            float4 av = make_float4(0.f, 0.f, 0.f, 0.f);
            if (grow < M) av = *(const float4*)(A + (size_t)grow * K + kk + ak);
            As[ak + 0][r] = av.x; As[ak + 1][r] = av.y;
            As[ak + 2][r] = av.z; As[ak + 3][r] = av.w;
        }
        {
            const float* wp = W + (size_t)(kk + wk) * 256 + lb + wc;
            float4 w0 = *(const float4*)wp;
            float4 w1 = *(const float4*)(wp + 4);
            *(float4*)&Ws[wk][wc] = w0;
            *(float4*)&Ws[wk][wc + 4] = w1;
        }
        __syncthreads();
#pragma unroll
        for (int k = 0; k < 16; k++) {
            float a[8], b[8];
#pragma unroll
            for (int i = 0; i < 8; i++) a[i] = As[k][ty * 8 + i];
#pragma unroll
            for (int j = 0; j < 8; j++) b[j] = Ws[k][tx * 8 + j];
#pragma unroll
            for (int i = 0; i < 8; i++)
#pragma unroll
                for (int j = 0; j < 8; j++) acc[i][j] += a[i] * b[j];
        }
        __syncthreads();
    }
#pragma unroll
    for (int i = 0; i < 8; i++) {
        int row = rowbase + ty * 8 + i;
        if (row >= M) continue;
        __hip_bfloat16* cp = O + (size_t)row * 256 + lb + tx * 8;
#pragma unroll
        for (int j = 0; j < 8; j++)
            cp[j] = __float2bfloat16(acc[i][j] + bias[lb + tx * 8 + j]);
    }
}

// ---------- scores in CSR order + per-head max partials ----------
__global__ __launch_bounds__(256) void score2_kernel(
    const __hip_bfloat16* __restrict__ qb, const __hip_bfloat16* __restrict__ kb,
    const int* __restrict__ src_s, const int* __restrict__ dst_s,
    const float* __restrict__ et_s, const float* __restrict__ node_time,
    const float* __restrict__ Wt, const float* __restrict__ bt,
    float* __restrict__ scores, unsigned* __restrict__ partialmax)
{
    __shared__ unsigned smax[8];
    int tid = threadIdx.x;
    if (tid < 8) smax[tid] = 0u;
    __syncthreads();
    const int total = NUM_EDGES * 8;
    int t0 = blockIdx.x * 256 + tid;
    int stride = gridDim.x * 256;    // multiple of 8 -> h constant
    int h = t0 & 7;
    float wt0 = Wt[h], wt1 = Wt[8 + h], btv = bt[h];
    unsigned mykey = 0u;
    for (int t = t0; t < total; t += stride) {
        int pos = t >> 3;
        int s = src_s[pos], d = dst_s[pos];
        const ushort8* qp = (const ushort8*)(qb + (size_t)d * 256 + h * 32);
        const ushort8* kp = (const ushort8*)(kb + (size_t)s * 256 + h * 32);
        float dotv = 0.f;
#pragma unroll
        for (int i = 0; i < 4; i++) {
            ushort8 a = qp[i], b = kp[i];
#pragma unroll
            for (int j = 0; j < 8; j++) dotv += bf2f(a[j]) * bf2f(b[j]);
        }
        float td = et_s[pos] - node_time[d];
        float tf0 = (td > 0.f) ? 1.f : ((td < 0.f) ? -1.f : 0.f);
        float tf1 = log1pf(fabsf(td) * (1.f / 3600.f));
        float sc = dotv * 0.17677669529663687f + (tf0 * wt0 + tf1 * wt1 + btv);
        scores[t] = sc;
        unsigned kkey = float_to_key(sc);
        mykey = (kkey > mykey) ? kkey : mykey;
    }
    atomicMax(&smax[h], mykey);
    __syncthreads();
    if (tid < 8) partialmax[blockIdx.x * 8 + tid] = smax[tid];
}

__global__ __launch_bounds__(256) void reduce_max_kernel(
    const unsigned* __restrict__ partialmax, float* __restrict__ headmax)
{
    int tid = threadIdx.x;
    int h = tid >> 5, lane = tid & 31;
    unsigned m = 0u;
    for (int i = lane; i < 1024; i += 32) {
        unsigned v = partialmax[i * 8 + h];
        m = (v > m) ? v : m;
    }
    for (int off = 16; off > 0; off >>= 1) {
        unsigned o = __shfl_down(m, off, 32);
        m = (o > m) ? o : m;
    }
    if (lane == 0) headmax[h] = key_to_float(m);
}

// ---------- fused exp + aggregate (unscaled) + per-head sum partials ----------
__global__ __launch_bounds__(256) void aggregate2_kernel(
    const __hip_bfloat16* __restrict__ vb, const float* __restrict__ scores,
    const int* __restrict__ src_s, const int* __restrict__ offs,
    const float* __restrict__ headmax, float* __restrict__ agg,
    float* __restrict__ psum_part)
{
    __shared__ int ssrc[64];
    int n = blockIdx.x;
    int tid = threadIdx.x;
    int h = tid >> 5;
    float m = headmax[h];
    int start = offs[n], end = offs[n + 1];
    float acc = 0.f;
    float psum = 0.f;
    for (int cb = start; cb < end; cb += 64) {
        int cnt = min(64, end - cb);
        __syncthreads();
        if (tid < cnt) ssrc[tid] = src_s[cb + tid];
        __syncthreads();
        for (int j = 0; j < cnt; j++) {
            int pos = cb + j;
            int s = ssrc[j];
            float p = __expf(scores[(size_t)pos * 8 + h] - m);
            acc += p * bf2f(((const unsigned short*)vb)[(size_t)s * 256 + tid]);
            psum += p;
        }
    }
    agg[(size_t)n * 256 + tid] = acc;
    if ((tid & 31) == 0) psum_part[(size_t)n * 8 + h] = psum;
}

// ---------- reduce per-head sums (two stages) ----------
__global__ __launch_bounds__(256) void reduce_sum_stage1(
    const float* __restrict__ psum_part, float* __restrict__ partial2)
{
    __shared__ float ssum[8];
    int tid = threadIdx.x;
    if (tid < 8) ssum[tid] = 0.f;
    __syncthreads();
    const int total = NUM_NODES * 8;
    int t0 = blockIdx.x * 256 + tid;
    int stride = gridDim.x * 256;    // multiple of 8
    int h = t0 & 7;
    float s = 0.f;
    for (int t = t0; t < total; t += stride) s += psum_part[t];
    atomicAdd(&ssum[h], s);
    __syncthreads();
    if (tid < 8) partial2[blockIdx.x * 8 + tid] = ssum[tid];
}

__global__ __launch_bounds__(256) void reduce_sum_final(
    const float* __restrict__ partial2, float* __restrict__ headinv)
{
    int tid = threadIdx.x;
    int h = tid >> 5, lane = tid & 31;
    float s = 0.f;
    for (int i = lane; i < 256; i += 32) s += partial2[i * 8 + h];
    for (int off = 16; off > 0; off >>= 1) s += __shfl_down(s, off, 32);
    if (lane == 0) headinv[h] = 1.f / s;
}

// ---------- output GEMM: A=agg fp32 scaled per k-head, B=Wo, out fp32 ----------
__global__ __launch_bounds__(256) void gemm_out_kernel(
    const float* __restrict__ A, int M,
    const float* __restrict__ W, const float* __restrict__ bias,
    const float* __restrict__ kscale, float* __restrict__ C)
{
    const int K = 256;
    __shared__ float As[16][132];
    __shared__ float Ws[16][132];
    int tid = threadIdx.x;
    int colbase = blockIdx.x * 128;   // 0 or 128
    int rowbase = blockIdx.y * 128;
    int tx = tid & 15, ty = tid >> 4;

    float acc[8][8];
#pragma unroll
    for (int i = 0; i < 8; i++)
#pragma unroll
        for (int j = 0; j < 8; j++) acc[i][j] = 0.f;

    int ar = tid >> 2;
    int ak = (tid & 3) * 4;
    int wk = tid >> 4;
    int wc = (tid & 15) * 8;

    for (int kk = 0; kk < K; kk += 16) {
        float ks0 = kscale[(kk + ak) >> 5];
#pragma unroll
        for (int rr = 0; rr < 2; rr++) {
            int r = ar + rr * 64;
            int grow = rowbase + r;
            float4 av = make_float4(0.f, 0.f, 0.f, 0.f);
            if (grow < M) av = *(const float4*)(A + (size_t)grow * K + kk + ak);
            As[ak + 0][r] = av.x * ks0; As[ak + 1][r] = av.y * ks0;
            As[ak + 2][r] = av.z * ks0; As[ak + 3][r] = av.w * ks0;
        }
        {
            const float* wp = W + (size_t)(kk + wk) * 256 + colbase + wc;
            float4 w0 = *(const float4*)wp;
            float4 w1 = *(const float4*)(wp + 4);
            *(float4*)&Ws[wk][wc] = w0;
            *(float4*)&Ws[wk][wc + 4] = w1;
        }
        __syncthreads();
#pragma unroll
        for (int k = 0; k < 16; k++) {
            float a[8], b[8];
#pragma unroll
            for (int i = 0; i < 8; i++) a[i] = As[k][ty * 8 + i];
#pragma unroll
            for (int j = 0; j < 8; j++) b[j] = Ws[k][tx * 8 + j];
#pragma unroll
            for (int i = 0; i < 8; i++)
#pragma unroll
                for (int j = 0; j < 8; j++) acc[i][j] += a[i] * b[j];
        }
        __syncthreads();
    }
#pragma unroll
    for (int i = 0; i < 8; i++) {
        int row = rowbase + ty * 8 + i;
        if (row >= M) continue;
        float* cp = C + (size_t)row * 256 + colbase + tx * 8;
#pragma unroll
        for (int j = 0; j < 8; j++) cp[j] = acc[i][j] + bias[colbase + tx * 8 + j];
    }
}

extern "C" void kernel_launch(void* const* d_in, const int* in_sizes, int n_in,
                              void* d_out, int out_size, void* d_ws, size_t ws_size,
                              hipStream_t stream) {
    const float* x = (const float*)d_in[0];
    const int* ei = (const int*)d_in[1];
    const int* src_idx = ei;
    const int* dst_idx = ei + NUM_EDGES;
    const float* edge_time = (const float*)d_in[2];
    const float* node_time = (const float*)d_in[3];
    const float* Wq = (const float*)d_in[4];  const float* bq = (const float*)d_in[5];
    const float* Wk = (const float*)d_in[6];  const float* bk = (const float*)d_in[7];
    const float* Wv = (const float*)d_in[8];  const float* bv = (const float*)d_in[9];
    const float* Wt = (const float*)d_in[10]; const float* bt = (const float*)d_in[11];
    const float* Wo = (const float*)d_in[12]; const float* bo = (const float*)d_in[13];
    float* out = (float*)d_out;

    char* w = (char*)d_ws;
    __hip_bfloat16* qb = (__hip_bfloat16*)w; w += (size_t)NUM_NODES * 256 * 2;
    __hip_bfloat16* kb = (__hip_bfloat16*)w; w += (size_t)NUM_NODES * 256 * 2;
    __hip_bfloat16* vb = (__hip_bfloat16*)w; w += (size_t)NUM_NODES * 256 * 2;
    float* scores = (float*)w;      w += (size_t)NUM_EDGES * 8 * 4;
    float* agg = (float*)w;         w += (size_t)NUM_NODES * 256 * 4;
    int* src_s = (int*)w;           w += (size_t)NUM_EDGES * 4;
    int* dst_s = (int*)w;           w += (size_t)NUM_EDGES * 4;
    float* et_s = (float*)w;        w += (size_t)NUM_EDGES * 4;
    int* deg = (int*)w;             w += (size_t)NUM_NODES * 4;
    int* offs = (int*)w;            w += (size_t)(NUM_NODES + 1) * 4;
    int* cursor = (int*)w;          w += (size_t)NUM_NODES * 4;
    unsigned* partialmax = (unsigned*)w; w += 1024 * 8 * 4;
    float* psum_part = (float*)w;   w += (size_t)NUM_NODES * 8 * 4;
    float* partial2 = (float*)w;    w += 256 * 8 * 4;
    float* headmax = (float*)w;     w += 8 * 4;
    float* headinv = (float*)w;     w += 8 * 4;

    hipMemsetAsync(deg, 0, (size_t)NUM_NODES * 4, stream);

    // CSR by dst (+ gathered src/dst/time in CSR order)
    deg_kernel<<<(NUM_EDGES + 255) / 256, 256, 0, stream>>>(dst_idx, deg);
    scan_kernel<<<1, 1024, 0, stream>>>(deg, offs, cursor);
    fill2_kernel<<<(NUM_EDGES + 255) / 256, 256, 0, stream>>>(src_idx, dst_idx, edge_time,
                                                              cursor, src_s, dst_s, et_s);

    // QKV projection -> bf16 q/k/v
    dim3 gq(6, (NUM_NODES + 127) / 128);
    gemm_qkv_kernel<<<gq, 256, 0, stream>>>(x, NUM_NODES, Wq, Wk, Wv, bq, bk, bv, qb, kb, vb);

    // scores (CSR order) + per-head max
    score2_kernel<<<1024, 256, 0, stream>>>(qb, kb, src_s, dst_s, et_s, node_time,
                                            Wt, bt, scores, partialmax);
    reduce_max_kernel<<<1, 256, 0, stream>>>(partialmax, headmax);

    // fused exp + aggregate + per-head sum partials
    aggregate2_kernel<<<NUM_NODES, 256, 0, stream>>>(vb, scores, src_s, offs, headmax,
                                                     agg, psum_part);
    reduce_sum_stage1<<<256, 256, 0, stream>>>(psum_part, partial2);
    reduce_sum_final<<<1, 256, 0, stream>>>(partial2, headinv);

    // output projection with per-head 1/sum folded into A
    dim3 go(2, (NUM_NODES + 127) / 128);
    gemm_out_kernel<<<go, 256, 0, stream>>>(agg, NUM_NODES, Wo, bo, headinv, out);
}

// Round 3
// 549.940 us; speedup vs baseline: 2.1370x; 1.2891x over previous
//
#include <hip/hip_runtime.h>
#include <hip/hip_bf16.h>

#define NUM_NODES 50000
#define NUM_EDGES 800000
#define NUM_HEADS 8
#define HEAD_DIM 32

typedef unsigned short ushort8 __attribute__((ext_vector_type(8)));
typedef float f32x4 __attribute__((ext_vector_type(4)));
typedef __bf16 bf16x8 __attribute__((ext_vector_type(8)));

union BF8 { ushort8 u; bf16x8 b; };

__device__ __forceinline__ unsigned float_to_key(float f) {
    int i = __float_as_int(f);
    return (i >= 0) ? ((unsigned)i | 0x80000000u) : ~(unsigned)i;
}
__device__ __forceinline__ float key_to_float(unsigned u) {
    unsigned b = (u & 0x80000000u) ? (u & 0x7fffffffu) : ~u;
    return __int_as_float((int)b);
}
__device__ __forceinline__ float bf2f(unsigned short u) {
    return __uint_as_float(((unsigned)u) << 16);
}
__device__ __forceinline__ unsigned short f2bf(float f) {
    unsigned u = __float_as_uint(f);
    unsigned r = (u + 0x7fffu + ((u >> 16) & 1u)) >> 16;
    return (unsigned short)r;
}

// ---------- CSR build ----------
__global__ __launch_bounds__(256) void deg_kernel(const int* __restrict__ dst_idx, int* __restrict__ deg) {
    int e = blockIdx.x * 256 + threadIdx.x;
    if (e < NUM_EDGES) atomicAdd(&deg[dst_idx[e]], 1);
}

__global__ __launch_bounds__(1024) void scan_kernel(
    const int* __restrict__ deg, int* __restrict__ offs, int* __restrict__ cursor)
{
    __shared__ int buf[1024];
    __shared__ int carry;
    int tid = threadIdx.x;
    if (tid == 0) carry = 0;
    __syncthreads();
    for (int base = 0; base < NUM_NODES; base += 1024) {
        int i = base + tid;
        int v = (i < NUM_NODES) ? deg[i] : 0;
        buf[tid] = v;
        __syncthreads();
        for (int off = 1; off < 1024; off <<= 1) {
            int t = (tid >= off) ? buf[tid - off] : 0;
            __syncthreads();
            buf[tid] += t;
            __syncthreads();
        }
        int excl = buf[tid] - v;
        if (i < NUM_NODES) { offs[i] = carry + excl; cursor[i] = carry + excl; }
        __syncthreads();
        if (tid == 0) carry += buf[1023];
        __syncthreads();
    }
    if (tid == 0) offs[NUM_NODES] = carry;
}

__global__ __launch_bounds__(256) void fill2_kernel(
    const int* __restrict__ src_idx, const int* __restrict__ dst_idx,
    const float* __restrict__ edge_time, int* __restrict__ cursor,
    int* __restrict__ src_s, int* __restrict__ dst_s, float* __restrict__ et_s)
{
    int e = blockIdx.x * 256 + threadIdx.x;
    if (e < NUM_EDGES) {
        int d = dst_idx[e];
        int pos = atomicAdd(&cursor[d], 1);
        src_s[pos] = src_idx[e];
        dst_s[pos] = d;
        et_s[pos] = edge_time[e];
    }
}

// ---------- weight transpose+cvt: Wt[1024 n][256 k] bf16, rows g*256+n, g in {q,k,v,o} ----------
__global__ __launch_bounds__(256) void wtrans_kernel(
    const float* __restrict__ Wq, const float* __restrict__ Wk,
    const float* __restrict__ Wv, const float* __restrict__ Wo,
    unsigned short* __restrict__ Wt)
{
    __shared__ float t[64][65];
    int nb = blockIdx.x * 64;
    int kb = blockIdx.y * 64;
    int g = nb >> 8;
    const float* W = (g == 0) ? Wq : (g == 1) ? Wk : (g == 2) ? Wv : Wo;
    int n0 = nb & 255;
    int tx = threadIdx.x & 63;
    int ty = threadIdx.x >> 6;
#pragma unroll
    for (int i = 0; i < 16; i++) {
        int k = i * 4 + ty;
        t[tx][k] = W[(size_t)(kb + k) * 256 + n0 + tx];
    }
    __syncthreads();
#pragma unroll
    for (int i = 0; i < 16; i++) {
        int n = i * 4 + ty;
        Wt[(size_t)(nb + n) * 256 + kb + tx] = f2bf(t[n][tx]);
    }
}

// ---------- QKV GEMM via MFMA: A fp32 [M][256], Wt bf16 [n][k], out bf16 ----------
__global__ __launch_bounds__(256) void gemm_qkv_mfma(
    const float* __restrict__ A, int M,
    const unsigned short* __restrict__ Wt,
    const float* __restrict__ b0, const float* __restrict__ b1, const float* __restrict__ b2,
    unsigned short* __restrict__ O0, unsigned short* __restrict__ O1, unsigned short* __restrict__ O2)
{
    int tid = threadIdx.x;
    int lane = tid & 63;
    int wid = tid >> 6;
    int l16 = lane & 15;
    int kg = lane >> 4;
    int wm = wid >> 1, wn = wid & 1;
    int rowb = blockIdx.y * 128 + wm * 64;
    int colb = blockIdx.x * 128 + wn * 64;     // global col in [0,768)
    int g = colb >> 8;
    int lcb = colb & 255;
    const float* bias = (g == 0) ? b0 : (g == 1) ? b1 : b2;
    unsigned short* O = (g == 0) ? O0 : (g == 1) ? O1 : O2;

    f32x4 acc[4][4];
#pragma unroll
    for (int m = 0; m < 4; m++)
#pragma unroll
        for (int n = 0; n < 4; n++) acc[m][n] = (f32x4)(0.0f);

    int arow[4];
    unsigned short amask[4];
    const float* ap[4];
    const unsigned short* wp[4];
#pragma unroll
    for (int m = 0; m < 4; m++) {
        arow[m] = rowb + m * 16 + l16;
        bool ok = arow[m] < M;
        amask[m] = ok ? 0xffffu : 0u;
        ap[m] = A + (size_t)(ok ? arow[m] : 0) * 256 + kg * 8;
    }
#pragma unroll
    for (int n = 0; n < 4; n++)
        wp[n] = Wt + (size_t)(colb + n * 16 + l16) * 256 + kg * 8;

    for (int kk = 0; kk < 256; kk += 32) {
        bf16x8 bfr[4];
#pragma unroll
        for (int n = 0; n < 4; n++) {
            BF8 t; t.u = *(const ushort8*)(wp[n] + kk);
            bfr[n] = t.b;
        }
        bf16x8 afr[4];
#pragma unroll
        for (int m = 0; m < 4; m++) {
            float4 lo = *(const float4*)(ap[m] + kk);
            float4 hi = *(const float4*)(ap[m] + kk + 4);
            BF8 t;
            t.u[0] = f2bf(lo.x); t.u[1] = f2bf(lo.y); t.u[2] = f2bf(lo.z); t.u[3] = f2bf(lo.w);
            t.u[4] = f2bf(hi.x); t.u[5] = f2bf(hi.y); t.u[6] = f2bf(hi.z); t.u[7] = f2bf(hi.w);
            t.u &= amask[m];
            afr[m] = t.b;
        }
#pragma unroll
        for (int m = 0; m < 4; m++)
#pragma unroll
            for (int n = 0; n < 4; n++)
                acc[m][n] = __builtin_amdgcn_mfma_f32_16x16x32_bf16(bfr[n], afr[m], acc[m][n], 0, 0, 0);
    }

#pragma unroll
    for (int m = 0; m < 4; m++) {
        if (!amask[m]) continue;
        int node = arow[m];
#pragma unroll
        for (int n = 0; n < 4; n++) {
            int lc = lcb + n * 16 + kg * 4;
            float4 bv = *(const float4*)(bias + lc);
            ushort4 o;
            o.x = f2bf(acc[m][n][0] + bv.x);
            o.y = f2bf(acc[m][n][1] + bv.y);
            o.z = f2bf(acc[m][n][2] + bv.z);
            o.w = f2bf(acc[m][n][3] + bv.w);
            *(ushort4*)(O + (size_t)node * 256 + lc) = o;
        }
    }
}

// ---------- output GEMM via MFMA: A=agg fp32 scaled per k-head, out fp32 ----------
__global__ __launch_bounds__(256) void gemm_out_mfma(
    const float* __restrict__ A, int M,
    const unsigned short* __restrict__ Wt,    // Wo rows: [n][k]
    const float* __restrict__ bias, const float* __restrict__ kscale,
    float* __restrict__ C)
{
    int tid = threadIdx.x;
    int lane = tid & 63;
    int wid = tid >> 6;
    int l16 = lane & 15;
    int kg = lane >> 4;
    int wm = wid >> 1, wn = wid & 1;
    int rowb = blockIdx.y * 128 + wm * 64;
    int colb = blockIdx.x * 128 + wn * 64;    // [0,256)

    float ksv[8];
#pragma unroll
    for (int i = 0; i < 8; i++) ksv[i] = kscale[i];

    f32x4 acc[4][4];
#pragma unroll
    for (int m = 0; m < 4; m++)
#pragma unroll
        for (int n = 0; n < 4; n++) acc[m][n] = (f32x4)(0.0f);

    int arow[4];
    unsigned short amask[4];
    const float* ap[4];
    const unsigned short* wp[4];
#pragma unroll
    for (int m = 0; m < 4; m++) {
        arow[m] = rowb + m * 16 + l16;
        bool ok = arow[m] < M;
        amask[m] = ok ? 0xffffu : 0u;
        ap[m] = A + (size_t)(ok ? arow[m] : 0) * 256 + kg * 8;
    }
#pragma unroll
    for (int n = 0; n < 4; n++)
        wp[n] = Wt + (size_t)(colb + n * 16 + l16) * 256 + kg * 8;

#pragma unroll
    for (int kk = 0; kk < 256; kk += 32) {
        float ks = ksv[kk >> 5];
        bf16x8 bfr[4];
#pragma unroll
        for (int n = 0; n < 4; n++) {
            BF8 t; t.u = *(const ushort8*)(wp[n] + kk);
            bfr[n] = t.b;
        }
        bf16x8 afr[4];
#pragma unroll
        for (int m = 0; m < 4; m++) {
            float4 lo = *(const float4*)(ap[m] + kk);
            float4 hi = *(const float4*)(ap[m] + kk + 4);
            BF8 t;
            t.u[0] = f2bf(lo.x * ks); t.u[1] = f2bf(lo.y * ks);
            t.u[2] = f2bf(lo.z * ks); t.u[3] = f2bf(lo.w * ks);
            t.u[4] = f2bf(hi.x * ks); t.u[5] = f2bf(hi.y * ks);
            t.u[6] = f2bf(hi.z * ks); t.u[7] = f2bf(hi.w * ks);
            t.u &= amask[m];
            afr[m] = t.b;
        }
#pragma unroll
        for (int m = 0; m < 4; m++)
#pragma unroll
            for (int n = 0; n < 4; n++)
                acc[m][n] = __builtin_amdgcn_mfma_f32_16x16x32_bf16(bfr[n], afr[m], acc[m][n], 0, 0, 0);
    }

#pragma unroll
    for (int m = 0; m < 4; m++) {
        if (!amask[m]) continue;
        int node = arow[m];
#pragma unroll
        for (int n = 0; n < 4; n++) {
            int col = colb + n * 16 + kg * 4;
            float4 bv = *(const float4*)(bias + col);
            float4 o;
            o.x = acc[m][n][0] + bv.x;
            o.y = acc[m][n][1] + bv.y;
            o.z = acc[m][n][2] + bv.z;
            o.w = acc[m][n][3] + bv.w;
            *(float4*)(C + (size_t)node * 256 + col) = o;
        }
    }
}

// ---------- scores in CSR order + per-head max partials ----------
__global__ __launch_bounds__(256) void score2_kernel(
    const unsigned short* __restrict__ qb, const unsigned short* __restrict__ kb,
    const int* __restrict__ src_s, const int* __restrict__ dst_s,
    const float* __restrict__ et_s, const float* __restrict__ node_time,
    const float* __restrict__ Wt, const float* __restrict__ bt,
    float* __restrict__ scores, unsigned* __restrict__ partialmax)
{
    __shared__ unsigned smax[8];
    int tid = threadIdx.x;
    if (tid < 8) smax[tid] = 0u;
    __syncthreads();
    const int total = NUM_EDGES * 8;
    int t0 = blockIdx.x * 256 + tid;
    int stride = gridDim.x * 256;
    int h = t0 & 7;
    float wt0 = Wt[h], wt1 = Wt[8 + h], btv = bt[h];
    unsigned mykey = 0u;
    for (int t = t0; t < total; t += stride) {
        int pos = t >> 3;
        int s = src_s[pos], d = dst_s[pos];
        const ushort8* qp = (const ushort8*)(qb + (size_t)d * 256 + h * 32);
        const ushort8* kp = (const ushort8*)(kb + (size_t)s * 256 + h * 32);
        float dotv = 0.f;
#pragma unroll
        for (int i = 0; i < 4; i++) {
            ushort8 a = qp[i], b = kp[i];
#pragma unroll
            for (int j = 0; j < 8; j++) dotv += bf2f(a[j]) * bf2f(b[j]);
        }
        float td = et_s[pos] - node_time[d];
        float tf0 = (td > 0.f) ? 1.f : ((td < 0.f) ? -1.f : 0.f);
        float tf1 = log1pf(fabsf(td) * (1.f / 3600.f));
        float sc = dotv * 0.17677669529663687f + (tf0 * wt0 + tf1 * wt1 + btv);
        scores[t] = sc;
        unsigned kkey = float_to_key(sc);
        mykey = (kkey > mykey) ? kkey : mykey;
    }
    atomicMax(&smax[h], mykey);
    __syncthreads();
    if (tid < 8) partialmax[blockIdx.x * 8 + tid] = smax[tid];
}

__global__ __launch_bounds__(256) void reduce_max_kernel(
    const unsigned* __restrict__ partialmax, float* __restrict__ headmax)
{
    int tid = threadIdx.x;
    int h = tid >> 5, lane = tid & 31;
    unsigned m = 0u;
    for (int i = lane; i < 1024; i += 32) {
        unsigned v = partialmax[i * 8 + h];
        m = (v > m) ? v : m;
    }
    for (int off = 16; off > 0; off >>= 1) {
        unsigned o = __shfl_down(m, off, 32);
        m = (o > m) ? o : m;
    }
    if (lane == 0) headmax[h] = key_to_float(m);
}

// ---------- fused exp + aggregate (unscaled) + per-head sum partials ----------
__global__ __launch_bounds__(256) void aggregate2_kernel(
    const unsigned short* __restrict__ vb, const float* __restrict__ scores,
    const int* __restrict__ src_s, const int* __restrict__ offs,
    const float* __restrict__ headmax, float* __restrict__ agg,
    float* __restrict__ psum_part)
{
    __shared__ int ssrc[64];
    int n = blockIdx.x;
    int tid = threadIdx.x;
    int h = tid >> 5;
    float m = headmax[h];
    int start = offs[n], end = offs[n + 1];
    float acc = 0.f;
    float psum = 0.f;
    for (int cb = start; cb < end; cb += 64) {
        int cnt = min(64, end - cb);
        __syncthreads();
        if (tid < cnt) ssrc[tid] = src_s[cb + tid];
        __syncthreads();
        for (int j = 0; j < cnt; j++) {
            int pos = cb + j;
            int s = ssrc[j];
            float p = __expf(scores[(size_t)pos * 8 + h] - m);
            acc += p * bf2f(vb[(size_t)s * 256 + tid]);
            psum += p;
        }
    }
    agg[(size_t)n * 256 + tid] = acc;
    if ((tid & 31) == 0) psum_part[(size_t)n * 8 + h] = psum;
}

__global__ __launch_bounds__(256) void reduce_sum_stage1(
    const float* __restrict__ psum_part, float* __restrict__ partial2)
{
    __shared__ float ssum[8];
    int tid = threadIdx.x;
    if (tid < 8) ssum[tid] = 0.f;
    __syncthreads();
    const int total = NUM_NODES * 8;
    int t0 = blockIdx.x * 256 + tid;
    int stride = gridDim.x * 256;
    int h = t0 & 7;
    float s = 0.f;
    for (int t = t0; t < total; t += stride) s += psum_part[t];
    atomicAdd(&ssum[h], s);
    __syncthreads();
    if (tid < 8) partial2[blockIdx.x * 8 + tid] = ssum[tid];
}

__global__ __launch_bounds__(256) void reduce_sum_final(
    const float* __restrict__ partial2, float* __restrict__ headinv)
{
    int tid = threadIdx.x;
    int h = tid >> 5, lane = tid & 31;
    float s = 0.f;
    for (int i = lane; i < 256; i += 32) s += partial2[i * 8 + h];
    for (int off = 16; off > 0; off >>= 1) s += __shfl_down(s, off, 32);
    if (lane == 0) headinv[h] = 1.f / s;
}

extern "C" void kernel_launch(void* const* d_in, const int* in_sizes, int n_in,
                              void* d_out, int out_size, void* d_ws, size_t ws_size,
                              hipStream_t stream) {
    const float* x = (const float*)d_in[0];
    const int* ei = (const int*)d_in[1];
    const int* src_idx = ei;
    const int* dst_idx = ei + NUM_EDGES;
    const float* edge_time = (const float*)d_in[2];
    const float* node_time = (const float*)d_in[3];
    const float* Wq = (const float*)d_in[4];  const float* bq = (const float*)d_in[5];
    const float* Wk = (const float*)d_in[6];  const float* bk = (const float*)d_in[7];
    const float* Wv = (const float*)d_in[8];  const float* bv = (const float*)d_in[9];
    const float* Wt = (const float*)d_in[10]; const float* bt = (const float*)d_in[11];
    const float* Wo = (const float*)d_in[12]; const float* bo = (const float*)d_in[13];
    float* out = (float*)d_out;

    char* w = (char*)d_ws;
    unsigned short* qb = (unsigned short*)w; w += (size_t)NUM_NODES * 256 * 2;
    unsigned short* kb = (unsigned short*)w; w += (size_t)NUM_NODES * 256 * 2;
    unsigned short* vb = (unsigned short*)w; w += (size_t)NUM_NODES * 256 * 2;
    float* scores = (float*)w;      w += (size_t)NUM_EDGES * 8 * 4;
    float* agg = (float*)w;         w += (size_t)NUM_NODES * 256 * 4;
    int* src_s = (int*)w;           w += (size_t)NUM_EDGES * 4;
    int* dst_s = (int*)w;           w += (size_t)NUM_EDGES * 4;
    float* et_s = (float*)w;        w += (size_t)NUM_EDGES * 4;
    int* deg = (int*)w;             w += (size_t)NUM_NODES * 4;
    int* offs = (int*)w;            w += (size_t)(NUM_NODES + 1) * 4;
    int* cursor = (int*)w;          w += (size_t)NUM_NODES * 4;
    unsigned* partialmax = (unsigned*)w; w += 1024 * 8 * 4;
    float* psum_part = (float*)w;   w += (size_t)NUM_NODES * 8 * 4;
    float* partial2 = (float*)w;    w += 256 * 8 * 4;
    float* headmax = (float*)w;     w += 8 * 4;
    float* headinv = (float*)w;     w += 8 * 4;
    unsigned short* Wtb = (unsigned short*)w; w += (size_t)1024 * 256 * 2;

    hipMemsetAsync(deg, 0, (size_t)NUM_NODES * 4, stream);

    // weight transpose + bf16 cvt (q,k,v,o)
    dim3 gw(16, 4);
    wtrans_kernel<<<gw, 256, 0, stream>>>(Wq, Wk, Wv, Wo, Wtb);

    // CSR by dst (+ gathered src/dst/time in CSR order)
    deg_kernel<<<(NUM_EDGES + 255) / 256, 256, 0, stream>>>(dst_idx, deg);
    scan_kernel<<<1, 1024, 0, stream>>>(deg, offs, cursor);
    fill2_kernel<<<(NUM_EDGES + 255) / 256, 256, 0, stream>>>(src_idx, dst_idx, edge_time,
                                                              cursor, src_s, dst_s, et_s);

    // QKV projection -> bf16 q/k/v  (MFMA)
    dim3 gq(6, (NUM_NODES + 127) / 128);
    gemm_qkv_mfma<<<gq, 256, 0, stream>>>(x, NUM_NODES, Wtb, bq, bk, bv, qb, kb, vb);

    // scores (CSR order) + per-head max
    score2_kernel<<<1024, 256, 0, stream>>>(qb, kb, src_s, dst_s, et_s, node_time,
                                            Wt, bt, scores, partialmax);
    reduce_max_kernel<<<1, 256, 0, stream>>>(partialmax, headmax);

    // fused exp + aggregate + per-head sum partials
    aggregate2_kernel<<<NUM_NODES, 256, 0, stream>>>(vb, scores, src_s, offs, headmax,
                                                     agg, psum_part);
    reduce_sum_stage1<<<256, 256, 0, stream>>>(psum_part, partial2);
    reduce_sum_final<<<1, 256, 0, stream>>>(partial2, headinv);

    // output projection with per-head 1/sum folded into A (MFMA)
    dim3 go(2, (NUM_NODES + 127) / 128);
    gemm_out_mfma<<<go, 256, 0, stream>>>(agg, NUM_NODES, Wtb + (size_t)768 * 256,
                                          bo, headinv, out);
}

// Round 4
// 534.264 us; speedup vs baseline: 2.1997x; 1.0293x over previous
//
#include <hip/hip_runtime.h>
#include <hip/hip_bf16.h>

#define NUM_NODES 50000
#define NUM_EDGES 800000
#define NUM_HEADS 8
#define HEAD_DIM 32

typedef unsigned short ushort8 __attribute__((ext_vector_type(8)));
typedef float f32x4 __attribute__((ext_vector_type(4)));
typedef __bf16 bf16x8 __attribute__((ext_vector_type(8)));

union BF8 { ushort8 u; bf16x8 b; };

__device__ __forceinline__ unsigned float_to_key(float f) {
    int i = __float_as_int(f);
    return (i >= 0) ? ((unsigned)i | 0x80000000u) : ~(unsigned)i;
}
__device__ __forceinline__ float key_to_float(unsigned u) {
    unsigned b = (u & 0x80000000u) ? (u & 0x7fffffffu) : ~u;
    return __int_as_float((int)b);
}
__device__ __forceinline__ float bf2f(unsigned short u) {
    return __uint_as_float(((unsigned)u) << 16);
}
__device__ __forceinline__ unsigned short f2bf(float f) {
    unsigned u = __float_as_uint(f);
    unsigned r = (u + 0x7fffu + ((u >> 16) & 1u)) >> 16;
    return (unsigned short)r;
}

// ---------- CSR build ----------
__global__ __launch_bounds__(256) void deg_kernel(const int* __restrict__ dst_idx, int* __restrict__ deg) {
    int e = blockIdx.x * 256 + threadIdx.x;
    if (e < NUM_EDGES) atomicAdd(&deg[dst_idx[e]], 1);
}

__global__ __launch_bounds__(1024) void scan_kernel(
    const int* __restrict__ deg, int* __restrict__ offs, int* __restrict__ cursor)
{
    __shared__ int buf[1024];
    __shared__ int carry;
    int tid = threadIdx.x;
    if (tid == 0) carry = 0;
    __syncthreads();
    for (int base = 0; base < NUM_NODES; base += 1024) {
        int i = base + tid;
        int v = (i < NUM_NODES) ? deg[i] : 0;
        buf[tid] = v;
        __syncthreads();
        for (int off = 1; off < 1024; off <<= 1) {
            int t = (tid >= off) ? buf[tid - off] : 0;
            __syncthreads();
            buf[tid] += t;
            __syncthreads();
        }
        int excl = buf[tid] - v;
        if (i < NUM_NODES) { offs[i] = carry + excl; cursor[i] = carry + excl; }
        __syncthreads();
        if (tid == 0) carry += buf[1023];
        __syncthreads();
    }
    if (tid == 0) offs[NUM_NODES] = carry;
}

__global__ __launch_bounds__(256) void fill2_kernel(
    const int* __restrict__ src_idx, const int* __restrict__ dst_idx,
    const float* __restrict__ edge_time, int* __restrict__ cursor,
    int* __restrict__ src_s, int* __restrict__ dst_s, float* __restrict__ et_s)
{
    int e = blockIdx.x * 256 + threadIdx.x;
    if (e < NUM_EDGES) {
        int d = dst_idx[e];
        int pos = atomicAdd(&cursor[d], 1);
        src_s[pos] = src_idx[e];
        dst_s[pos] = d;
        et_s[pos] = edge_time[e];
    }
}

// ---------- weight transpose+cvt: Wt[1024 n][256 k] bf16 ----------
__global__ __launch_bounds__(256) void wtrans_kernel(
    const float* __restrict__ Wq, const float* __restrict__ Wk,
    const float* __restrict__ Wv, const float* __restrict__ Wo,
    unsigned short* __restrict__ Wt)
{
    __shared__ float t[64][65];
    int nb = blockIdx.x * 64;
    int kb = blockIdx.y * 64;
    int g = nb >> 8;
    const float* W = (g == 0) ? Wq : (g == 1) ? Wk : (g == 2) ? Wv : Wo;
    int n0 = nb & 255;
    int tx = threadIdx.x & 63;
    int ty = threadIdx.x >> 6;
#pragma unroll
    for (int i = 0; i < 16; i++) {
        int k = i * 4 + ty;
        t[tx][k] = W[(size_t)(kb + k) * 256 + n0 + tx];
    }
    __syncthreads();
#pragma unroll
    for (int i = 0; i < 16; i++) {
        int n = i * 4 + ty;
        Wt[(size_t)(nb + n) * 256 + kb + tx] = f2bf(t[n][tx]);
    }
}

// ---------- QKV GEMM via MFMA, LDS-staged A (bf16, swizzled) ----------
// grid: (M+127)/128 row blocks. Each block computes all 768 output cols.
__global__ __launch_bounds__(256) void gemm_qkv_mfma2(
    const float* __restrict__ A, int M,
    const unsigned short* __restrict__ Wt,
    const float* __restrict__ b0, const float* __restrict__ b1, const float* __restrict__ b2,
    unsigned short* __restrict__ O0, unsigned short* __restrict__ O1, unsigned short* __restrict__ O2)
{
    __shared__ unsigned short As[128 * 256];   // 64 KB, 16B-chunk swizzle: c ^= (row&7)
    int tid = threadIdx.x;
    int rowbase = blockIdx.x * 128;

    // stage A -> bf16 LDS (each iter: 4 full rows, coalesced)
    {
        int rsub = tid >> 6;          // 0..3
        int c4 = (tid & 63) * 4;      // float col
        int cchunk = (tid & 63) >> 1; // 16B chunk
        int sub = (tid & 1);          // 8B half
#pragma unroll
        for (int it = 0; it < 32; it++) {
            int row = it * 4 + rsub;
            int grow = rowbase + row;
            float4 av = make_float4(0.f, 0.f, 0.f, 0.f);
            if (grow < M) av = *(const float4*)(A + (size_t)grow * 256 + c4);
            ushort4 o;
            o.x = f2bf(av.x); o.y = f2bf(av.y); o.z = f2bf(av.z); o.w = f2bf(av.w);
            unsigned byte = row * 512 + ((unsigned)(cchunk ^ (row & 7)) << 4) + sub * 8;
            *(ushort4*)((char*)As + byte) = o;
        }
    }
    __syncthreads();

    int lane = tid & 63;
    int wid = tid >> 6;
    int l16 = lane & 15;
    int kg = lane >> 4;
    int wm = wid & 1, wn = wid >> 1;

    // A rows for this wave's fragments
    int lrow[4];
#pragma unroll
    for (int m = 0; m < 4; m++) lrow[m] = wm * 64 + m * 16 + l16;

    for (int g6 = 0; g6 < 6; g6++) {
        int colb = g6 * 128 + wn * 64;
        int g = colb >> 8;
        int lcb = colb & 255;
        const float* bias = (g == 0) ? b0 : (g == 1) ? b1 : b2;
        unsigned short* O = (g == 0) ? O0 : (g == 1) ? O1 : O2;

        f32x4 acc[4][4];
#pragma unroll
        for (int m = 0; m < 4; m++)
#pragma unroll
            for (int n = 0; n < 4; n++) acc[m][n] = (f32x4)(0.0f);

        const unsigned short* wp[4];
#pragma unroll
        for (int n = 0; n < 4; n++)
            wp[n] = Wt + (size_t)(colb + n * 16 + l16) * 256 + kg * 8;

#pragma unroll
        for (int c2 = 0; c2 < 8; c2++) {
            bf16x8 wfr[4];
#pragma unroll
            for (int n = 0; n < 4; n++) {
                BF8 t; t.u = *(const ushort8*)(wp[n] + c2 * 32);
                wfr[n] = t.b;
            }
            bf16x8 afr[4];
#pragma unroll
            for (int m = 0; m < 4; m++) {
                int row = lrow[m];
                int cchunk = (c2 * 4 + kg) ^ (row & 7);
                BF8 t;
                t.u = *(const ushort8*)((const char*)As + row * 512 + (cchunk << 4));
                afr[m] = t.b;
            }
#pragma unroll
            for (int m = 0; m < 4; m++)
#pragma unroll
                for (int n = 0; n < 4; n++)
                    acc[m][n] = __builtin_amdgcn_mfma_f32_16x16x32_bf16(wfr[n], afr[m], acc[m][n], 0, 0, 0);
        }

#pragma unroll
        for (int m = 0; m < 4; m++) {
            int node = rowbase + wm * 64 + m * 16 + l16;
            if (node >= M) continue;
#pragma unroll
            for (int n = 0; n < 4; n++) {
                int lc = lcb + n * 16 + kg * 4;
                float4 bv = *(const float4*)(bias + lc);
                ushort4 o;
                o.x = f2bf(acc[m][n][0] + bv.x);
                o.y = f2bf(acc[m][n][1] + bv.y);
                o.z = f2bf(acc[m][n][2] + bv.z);
                o.w = f2bf(acc[m][n][3] + bv.w);
                *(ushort4*)(O + (size_t)node * 256 + lc) = o;
            }
        }
    }
}

// ---------- output GEMM via MFMA, LDS-staged A with per-head scale ----------
__global__ __launch_bounds__(256) void gemm_out_mfma2(
    const float* __restrict__ A, int M,
    const unsigned short* __restrict__ Wt,
    const float* __restrict__ bias, const float* __restrict__ kscale,
    float* __restrict__ C)
{
    __shared__ unsigned short As[128 * 256];
    int tid = threadIdx.x;
    int rowbase = blockIdx.x * 128;

    {
        int rsub = tid >> 6;
        int c4 = (tid & 63) * 4;
        int cchunk = (tid & 63) >> 1;
        int sub = (tid & 1);
        float ks = kscale[c4 >> 5];
#pragma unroll
        for (int it = 0; it < 32; it++) {
            int row = it * 4 + rsub;
            int grow = rowbase + row;
            float4 av = make_float4(0.f, 0.f, 0.f, 0.f);
            if (grow < M) av = *(const float4*)(A + (size_t)grow * 256 + c4);
            ushort4 o;
            o.x = f2bf(av.x * ks); o.y = f2bf(av.y * ks);
            o.z = f2bf(av.z * ks); o.w = f2bf(av.w * ks);
            unsigned byte = row * 512 + ((unsigned)(cchunk ^ (row & 7)) << 4) + sub * 8;
            *(ushort4*)((char*)As + byte) = o;
        }
    }
    __syncthreads();

    int lane = tid & 63;
    int wid = tid >> 6;
    int l16 = lane & 15;
    int kg = lane >> 4;
    int wm = wid & 1, wn = wid >> 1;

    int lrow[4];
#pragma unroll
    for (int m = 0; m < 4; m++) lrow[m] = wm * 64 + m * 16 + l16;

    for (int g2 = 0; g2 < 2; g2++) {
        int colb = g2 * 128 + wn * 64;

        f32x4 acc[4][4];
#pragma unroll
        for (int m = 0; m < 4; m++)
#pragma unroll
            for (int n = 0; n < 4; n++) acc[m][n] = (f32x4)(0.0f);

        const unsigned short* wp[4];
#pragma unroll
        for (int n = 0; n < 4; n++)
            wp[n] = Wt + (size_t)(colb + n * 16 + l16) * 256 + kg * 8;

#pragma unroll
        for (int c2 = 0; c2 < 8; c2++) {
            bf16x8 wfr[4];
#pragma unroll
            for (int n = 0; n < 4; n++) {
                BF8 t; t.u = *(const ushort8*)(wp[n] + c2 * 32);
                wfr[n] = t.b;
            }
            bf16x8 afr[4];
#pragma unroll
            for (int m = 0; m < 4; m++) {
                int row = lrow[m];
                int cchunk = (c2 * 4 + kg) ^ (row & 7);
                BF8 t;
                t.u = *(const ushort8*)((const char*)As + row * 512 + (cchunk << 4));
                afr[m] = t.b;
            }
#pragma unroll
            for (int m = 0; m < 4; m++)
#pragma unroll
                for (int n = 0; n < 4; n++)
                    acc[m][n] = __builtin_amdgcn_mfma_f32_16x16x32_bf16(wfr[n], afr[m], acc[m][n], 0, 0, 0);
        }

#pragma unroll
        for (int m = 0; m < 4; m++) {
            int node = rowbase + wm * 64 + m * 16 + l16;
            if (node >= M) continue;
#pragma unroll
            for (int n = 0; n < 4; n++) {
                int col = colb + n * 16 + kg * 4;
                float4 bv = *(const float4*)(bias + col);
                float4 o;
                o.x = acc[m][n][0] + bv.x;
                o.y = acc[m][n][1] + bv.y;
                o.z = acc[m][n][2] + bv.z;
                o.w = acc[m][n][3] + bv.w;
                *(float4*)(C + (size_t)node * 256 + col) = o;
            }
        }
    }
}

// ---------- scores in CSR order + per-head max partials ----------
__global__ __launch_bounds__(256) void score2_kernel(
    const unsigned short* __restrict__ qb, const unsigned short* __restrict__ kb,
    const int* __restrict__ src_s, const int* __restrict__ dst_s,
    const float* __restrict__ et_s, const float* __restrict__ node_time,
    const float* __restrict__ Wt, const float* __restrict__ bt,
    float* __restrict__ scores, unsigned* __restrict__ partialmax)
{
    __shared__ unsigned smax[8];
    int tid = threadIdx.x;
    if (tid < 8) smax[tid] = 0u;
    __syncthreads();
    const int total = NUM_EDGES * 8;
    int t0 = blockIdx.x * 256 + tid;
    int stride = gridDim.x * 256;
    int h = t0 & 7;
    float wt0 = Wt[h], wt1 = Wt[8 + h], btv = bt[h];
    unsigned mykey = 0u;
    for (int t = t0; t < total; t += stride) {
        int pos = t >> 3;
        int s = src_s[pos], d = dst_s[pos];
        const ushort8* qp = (const ushort8*)(qb + (size_t)d * 256 + h * 32);
        const ushort8* kp = (const ushort8*)(kb + (size_t)s * 256 + h * 32);
        float dotv = 0.f;
#pragma unroll
        for (int i = 0; i < 4; i++) {
            ushort8 a = qp[i], b = kp[i];
#pragma unroll
            for (int j = 0; j < 8; j++) dotv += bf2f(a[j]) * bf2f(b[j]);
        }
        float td = et_s[pos] - node_time[d];
        float tf0 = (td > 0.f) ? 1.f : ((td < 0.f) ? -1.f : 0.f);
        float tf1 = log1pf(fabsf(td) * (1.f / 3600.f));
        float sc = dotv * 0.17677669529663687f + (tf0 * wt0 + tf1 * wt1 + btv);
        scores[t] = sc;
        unsigned kkey = float_to_key(sc);
        mykey = (kkey > mykey) ? kkey : mykey;
    }
    atomicMax(&smax[h], mykey);
    __syncthreads();
    if (tid < 8) partialmax[blockIdx.x * 8 + tid] = smax[tid];
}

__global__ __launch_bounds__(256) void reduce_max_kernel(
    const unsigned* __restrict__ partialmax, float* __restrict__ headmax)
{
    int tid = threadIdx.x;
    int h = tid >> 5, lane = tid & 31;
    unsigned m = 0u;
    for (int i = lane; i < 1024; i += 32) {
        unsigned v = partialmax[i * 8 + h];
        m = (v > m) ? v : m;
    }
    for (int off = 16; off > 0; off >>= 1) {
        unsigned o = __shfl_down(m, off, 32);
        m = (o > m) ? o : m;
    }
    if (lane == 0) headmax[h] = key_to_float(m);
}

// ---------- fused exp + aggregate, exp staged in LDS once ----------
__global__ __launch_bounds__(256) void aggregate3_kernel(
    const unsigned short* __restrict__ vb, const float* __restrict__ scores,
    const int* __restrict__ src_s, const int* __restrict__ offs,
    const float* __restrict__ headmax, float* __restrict__ agg,
    float* __restrict__ psum_part)
{
    __shared__ int ssrc[64];
    __shared__ float pl[64 * 8];
    __shared__ float hm[8];
    int n = blockIdx.x;
    int tid = threadIdx.x;
    int h = tid >> 5;
    if (tid < 8) hm[tid] = headmax[tid];
    __syncthreads();
    float m = hm[h];
    int start = offs[n], end = offs[n + 1];
    float acc = 0.f;
    float psum = 0.f;
    for (int cb = start; cb < end; cb += 64) {
        int cnt = min(64, end - cb);
        __syncthreads();
        if (tid < cnt) ssrc[tid] = src_s[cb + tid];
        // stage exp(score - max): 512 values, 2 per thread, coalesced
        {
            int i0 = tid;
            int j0 = i0 >> 3;
            if (j0 < cnt) pl[i0] = __expf(scores[(size_t)(cb + j0) * 8 + (i0 & 7)] - hm[i0 & 7]);
            int i1 = tid + 256;
            int j1 = i1 >> 3;
            if (j1 < cnt) pl[i1] = __expf(scores[(size_t)(cb + j1) * 8 + (i1 & 7)] - hm[i1 & 7]);
        }
        __syncthreads();
        for (int j = 0; j < cnt; j++) {
            int s = ssrc[j];
            float p = pl[j * 8 + h];
            acc += p * bf2f(vb[(size_t)s * 256 + tid]);
            psum += p;
        }
    }
    agg[(size_t)n * 256 + tid] = acc;
    if ((tid & 31) == 0) psum_part[(size_t)n * 8 + h] = psum;
}

__global__ __launch_bounds__(256) void reduce_sum_stage1(
    const float* __restrict__ psum_part, float* __restrict__ partial2)
{
    __shared__ float ssum[8];
    int tid = threadIdx.x;
    if (tid < 8) ssum[tid] = 0.f;
    __syncthreads();
    const int total = NUM_NODES * 8;
    int t0 = blockIdx.x * 256 + tid;
    int stride = gridDim.x * 256;
    int h = t0 & 7;
    float s = 0.f;
    for (int t = t0; t < total; t += stride) s += psum_part[t];
    atomicAdd(&ssum[h], s);
    __syncthreads();
    if (tid < 8) partial2[blockIdx.x * 8 + tid] = ssum[tid];
}

__global__ __launch_bounds__(256) void reduce_sum_final(
    const float* __restrict__ partial2, float* __restrict__ headinv)
{
    int tid = threadIdx.x;
    int h = tid >> 5, lane = tid & 31;
    float s = 0.f;
    for (int i = lane; i < 256; i += 32) s += partial2[i * 8 + h];
    for (int off = 16; off > 0; off >>= 1) s += __shfl_down(s, off, 32);
    if (lane == 0) headinv[h] = 1.f / s;
}

extern "C" void kernel_launch(void* const* d_in, const int* in_sizes, int n_in,
                              void* d_out, int out_size, void* d_ws, size_t ws_size,
                              hipStream_t stream) {
    const float* x = (const float*)d_in[0];
    const int* ei = (const int*)d_in[1];
    const int* src_idx = ei;
    const int* dst_idx = ei + NUM_EDGES;
    const float* edge_time = (const float*)d_in[2];
    const float* node_time = (const float*)d_in[3];
    const float* Wq = (const float*)d_in[4];  const float* bq = (const float*)d_in[5];
    const float* Wk = (const float*)d_in[6];  const float* bk = (const float*)d_in[7];
    const float* Wv = (const float*)d_in[8];  const float* bv = (const float*)d_in[9];
    const float* Wt = (const float*)d_in[10]; const float* bt = (const float*)d_in[11];
    const float* Wo = (const float*)d_in[12]; const float* bo = (const float*)d_in[13];
    float* out = (float*)d_out;

    char* w = (char*)d_ws;
    unsigned short* qb = (unsigned short*)w; w += (size_t)NUM_NODES * 256 * 2;
    unsigned short* kb = (unsigned short*)w; w += (size_t)NUM_NODES * 256 * 2;
    unsigned short* vb = (unsigned short*)w; w += (size_t)NUM_NODES * 256 * 2;
    float* scores = (float*)w;      w += (size_t)NUM_EDGES * 8 * 4;
    float* agg = (float*)w;         w += (size_t)NUM_NODES * 256 * 4;
    int* src_s = (int*)w;           w += (size_t)NUM_EDGES * 4;
    int* dst_s = (int*)w;           w += (size_t)NUM_EDGES * 4;
    float* et_s = (float*)w;        w += (size_t)NUM_EDGES * 4;
    int* deg = (int*)w;             w += (size_t)NUM_NODES * 4;
    int* offs = (int*)w;            w += (size_t)(NUM_NODES + 1) * 4;
    int* cursor = (int*)w;          w += (size_t)NUM_NODES * 4;
    unsigned* partialmax = (unsigned*)w; w += 1024 * 8 * 4;
    float* psum_part = (float*)w;   w += (size_t)NUM_NODES * 8 * 4;
    float* partial2 = (float*)w;    w += 256 * 8 * 4;
    float* headmax = (float*)w;     w += 8 * 4;
    float* headinv = (float*)w;     w += 8 * 4;
    unsigned short* Wtb = (unsigned short*)w; w += (size_t)1024 * 256 * 2;

    hipMemsetAsync(deg, 0, (size_t)NUM_NODES * 4, stream);

    // weight transpose + bf16 cvt (q,k,v,o)
    dim3 gw(16, 4);
    wtrans_kernel<<<gw, 256, 0, stream>>>(Wq, Wk, Wv, Wo, Wtb);

    // CSR by dst (+ gathered src/dst/time in CSR order)
    deg_kernel<<<(NUM_EDGES + 255) / 256, 256, 0, stream>>>(dst_idx, deg);
    scan_kernel<<<1, 1024, 0, stream>>>(deg, offs, cursor);
    fill2_kernel<<<(NUM_EDGES + 255) / 256, 256, 0, stream>>>(src_idx, dst_idx, edge_time,
                                                              cursor, src_s, dst_s, et_s);

    // QKV projection -> bf16 q/k/v  (MFMA, LDS-staged A)
    gemm_qkv_mfma2<<<(NUM_NODES + 127) / 128, 256, 0, stream>>>(
        x, NUM_NODES, Wtb, bq, bk, bv, qb, kb, vb);

    // scores (CSR order) + per-head max
    score2_kernel<<<1024, 256, 0, stream>>>(qb, kb, src_s, dst_s, et_s, node_time,
                                            Wt, bt, scores, partialmax);
    reduce_max_kernel<<<1, 256, 0, stream>>>(partialmax, headmax);

    // fused exp + aggregate + per-head sum partials
    aggregate3_kernel<<<NUM_NODES, 256, 0, stream>>>(vb, scores, src_s, offs, headmax,
                                                     agg, psum_part);
    reduce_sum_stage1<<<256, 256, 0, stream>>>(psum_part, partial2);
    reduce_sum_final<<<1, 256, 0, stream>>>(partial2, headinv);

    // output projection with per-head 1/sum folded into A (MFMA, LDS-staged)
    gemm_out_mfma2<<<(NUM_NODES + 127) / 128, 256, 0, stream>>>(
        agg, NUM_NODES, Wtb + (size_t)768 * 256, bo, headinv, out);
}

// Round 5
// 414.246 us; speedup vs baseline: 2.8370x; 1.2897x over previous
//
#include <hip/hip_runtime.h>
#include <hip/hip_bf16.h>

#define NUM_NODES 50000
#define NUM_EDGES 800000
#define NUM_HEADS 8
#define HEAD_DIM 32
#define SCAN_BLOCKS 49

typedef unsigned short ushort8 __attribute__((ext_vector_type(8)));
typedef float f32x4 __attribute__((ext_vector_type(4)));
typedef __bf16 bf16x8 __attribute__((ext_vector_type(8)));

union BF8 { ushort8 u; bf16x8 b; };

__device__ __forceinline__ unsigned float_to_key(float f) {
    int i = __float_as_int(f);
    return (i >= 0) ? ((unsigned)i | 0x80000000u) : ~(unsigned)i;
}
__device__ __forceinline__ float key_to_float(unsigned u) {
    unsigned b = (u & 0x80000000u) ? (u & 0x7fffffffu) : ~u;
    return __int_as_float((int)b);
}
__device__ __forceinline__ float bf2f(unsigned short u) {
    return __uint_as_float(((unsigned)u) << 16);
}
__device__ __forceinline__ unsigned short f2bf(float f) {
    unsigned u = __float_as_uint(f);
    unsigned r = (u + 0x7fffu + ((u >> 16) & 1u)) >> 16;
    return (unsigned short)r;
}

// ---------- CSR build ----------
__global__ __launch_bounds__(256) void deg_kernel(const int* __restrict__ dst_idx, int* __restrict__ deg) {
    int e = blockIdx.x * 256 + threadIdx.x;
    if (e < NUM_EDGES) atomicAdd(&deg[dst_idx[e]], 1);
}

// local exclusive scan per 1024-block
__global__ __launch_bounds__(1024) void scanA_kernel(
    const int* __restrict__ deg, int* __restrict__ offs, int* __restrict__ blocksum)
{
    __shared__ int buf[1024];
    int tid = threadIdx.x;
    int i = blockIdx.x * 1024 + tid;
    int v = (i < NUM_NODES) ? deg[i] : 0;
    buf[tid] = v;
    __syncthreads();
    for (int off = 1; off < 1024; off <<= 1) {
        int t = (tid >= off) ? buf[tid - off] : 0;
        __syncthreads();
        buf[tid] += t;
        __syncthreads();
    }
    if (i < NUM_NODES) offs[i] = buf[tid] - v;
    if (tid == 1023) blocksum[blockIdx.x] = buf[1023];
}

__global__ __launch_bounds__(64) void scanB_kernel(
    const int* __restrict__ blocksum, int* __restrict__ carry, int* __restrict__ offs)
{
    if (threadIdx.x == 0) {
        int acc = 0;
        for (int b = 0; b < SCAN_BLOCKS; b++) { carry[b] = acc; acc += blocksum[b]; }
        offs[NUM_NODES] = acc;
    }
}

__global__ __launch_bounds__(256) void scanC_kernel(
    int* __restrict__ offs, const int* __restrict__ carry, int* __restrict__ cursor)
{
    int i = blockIdx.x * 256 + threadIdx.x;
    if (i < NUM_NODES) {
        int v = offs[i] + carry[i >> 10];
        offs[i] = v;
        cursor[i] = v;
    }
}

__global__ __launch_bounds__(256) void fill2_kernel(
    const int* __restrict__ src_idx, const int* __restrict__ dst_idx,
    const float* __restrict__ edge_time, int* __restrict__ cursor,
    int* __restrict__ src_s, int* __restrict__ dst_s, float* __restrict__ et_s)
{
    int e = blockIdx.x * 256 + threadIdx.x;
    if (e < NUM_EDGES) {
        int d = dst_idx[e];
        int pos = atomicAdd(&cursor[d], 1);
        src_s[pos] = src_idx[e];
        dst_s[pos] = d;
        et_s[pos] = edge_time[e];
    }
}

// ---------- weight transpose+cvt: Wt[1024 n][256 k] bf16 ----------
__global__ __launch_bounds__(256) void wtrans_kernel(
    const float* __restrict__ Wq, const float* __restrict__ Wk,
    const float* __restrict__ Wv, const float* __restrict__ Wo,
    unsigned short* __restrict__ Wt)
{
    __shared__ float t[64][65];
    int nb = blockIdx.x * 64;
    int kb = blockIdx.y * 64;
    int g = nb >> 8;
    const float* W = (g == 0) ? Wq : (g == 1) ? Wk : (g == 2) ? Wv : Wo;
    int n0 = nb & 255;
    int tx = threadIdx.x & 63;
    int ty = threadIdx.x >> 6;
#pragma unroll
    for (int i = 0; i < 16; i++) {
        int k = i * 4 + ty;
        t[tx][k] = W[(size_t)(kb + k) * 256 + n0 + tx];
    }
    __syncthreads();
#pragma unroll
    for (int i = 0; i < 16; i++) {
        int n = i * 4 + ty;
        Wt[(size_t)(nb + n) * 256 + kb + tx] = f2bf(t[n][tx]);
    }
}

// ---------- QKV GEMM via MFMA, 64-row tiles, LDS-staged A ----------
__global__ __launch_bounds__(256) void gemm_qkv_mfma3(
    const float* __restrict__ A, int M,
    const unsigned short* __restrict__ Wt,
    const float* __restrict__ b0, const float* __restrict__ b1, const float* __restrict__ b2,
    unsigned short* __restrict__ O0, unsigned short* __restrict__ O1, unsigned short* __restrict__ O2)
{
    __shared__ unsigned short As[64 * 256];   // 32 KB, 16B-chunk swizzle: c ^= (row&7)
    int tid = threadIdx.x;
    int rowbase = blockIdx.x * 64;

    // stage A -> bf16 LDS (OOB rows stage zeros)
    {
        int rsub = tid >> 6;          // 0..3
        int c4 = (tid & 63) * 4;
        int cchunk = (tid & 63) >> 1;
        int sub = (tid & 1);
#pragma unroll
        for (int it = 0; it < 16; it++) {
            int row = it * 4 + rsub;
            int grow = rowbase + row;
            float4 av = make_float4(0.f, 0.f, 0.f, 0.f);
            if (grow < M) av = *(const float4*)(A + (size_t)grow * 256 + c4);
            ushort4 o;
            o.x = f2bf(av.x); o.y = f2bf(av.y); o.z = f2bf(av.z); o.w = f2bf(av.w);
            unsigned byte = row * 512 + ((unsigned)(cchunk ^ (row & 7)) << 4) + sub * 8;
            *(ushort4*)((char*)As + byte) = o;
        }
    }
    __syncthreads();

    int lane = tid & 63;
    int wid = tid >> 6;      // wave owns cols [wid*64, wid*64+64)
    int l16 = lane & 15;
    int kg = lane >> 4;

#pragma unroll
    for (int p = 0; p < 3; p++) {      // q, k, v
        const float* bias = (p == 0) ? b0 : (p == 1) ? b1 : b2;
        unsigned short* O = (p == 0) ? O0 : (p == 1) ? O1 : O2;

        f32x4 acc[4][4];
#pragma unroll
        for (int m = 0; m < 4; m++)
#pragma unroll
            for (int n = 0; n < 4; n++) acc[m][n] = (f32x4)(0.0f);

        const unsigned short* wp[4];
#pragma unroll
        for (int n = 0; n < 4; n++)
            wp[n] = Wt + (size_t)(p * 256 + wid * 64 + n * 16 + l16) * 256 + kg * 8;

#pragma unroll
        for (int c2 = 0; c2 < 8; c2++) {
            bf16x8 wfr[4];
#pragma unroll
            for (int n = 0; n < 4; n++) {
                BF8 t; t.u = *(const ushort8*)(wp[n] + c2 * 32);
                wfr[n] = t.b;
            }
            bf16x8 afr[4];
#pragma unroll
            for (int m = 0; m < 4; m++) {
                int row = m * 16 + l16;
                int cchunk = (c2 * 4 + kg) ^ (row & 7);
                BF8 t;
                t.u = *(const ushort8*)((const char*)As + row * 512 + (cchunk << 4));
                afr[m] = t.b;
            }
#pragma unroll
            for (int m = 0; m < 4; m++)
#pragma unroll
                for (int n = 0; n < 4; n++)
                    acc[m][n] = __builtin_amdgcn_mfma_f32_16x16x32_bf16(wfr[n], afr[m], acc[m][n], 0, 0, 0);
        }

#pragma unroll
        for (int m = 0; m < 4; m++) {
            int node = rowbase + m * 16 + l16;
            if (node >= M) continue;
#pragma unroll
            for (int n = 0; n < 4; n++) {
                int lc = wid * 64 + n * 16 + kg * 4;
                float4 bv = *(const float4*)(bias + lc);
                ushort4 o;
                o.x = f2bf(acc[m][n][0] + bv.x);
                o.y = f2bf(acc[m][n][1] + bv.y);
                o.z = f2bf(acc[m][n][2] + bv.z);
                o.w = f2bf(acc[m][n][3] + bv.w);
                *(ushort4*)(O + (size_t)node * 256 + lc) = o;
            }
        }
    }
}

// ---------- output GEMM via MFMA, 64-row tiles, per-head scale in staging ----------
__global__ __launch_bounds__(256) void gemm_out_mfma3(
    const float* __restrict__ A, int M,
    const unsigned short* __restrict__ Wt,
    const float* __restrict__ bias, const float* __restrict__ kscale,
    float* __restrict__ C)
{
    __shared__ unsigned short As[64 * 256];
    int tid = threadIdx.x;
    int rowbase = blockIdx.x * 64;

    {
        int rsub = tid >> 6;
        int c4 = (tid & 63) * 4;
        int cchunk = (tid & 63) >> 1;
        int sub = (tid & 1);
        float ks = kscale[c4 >> 5];
#pragma unroll
        for (int it = 0; it < 16; it++) {
            int row = it * 4 + rsub;
            int grow = rowbase + row;
            float4 av = make_float4(0.f, 0.f, 0.f, 0.f);
            if (grow < M) av = *(const float4*)(A + (size_t)grow * 256 + c4);
            ushort4 o;
            o.x = f2bf(av.x * ks); o.y = f2bf(av.y * ks);
            o.z = f2bf(av.z * ks); o.w = f2bf(av.w * ks);
            unsigned byte = row * 512 + ((unsigned)(cchunk ^ (row & 7)) << 4) + sub * 8;
            *(ushort4*)((char*)As + byte) = o;
        }
    }
    __syncthreads();

    int lane = tid & 63;
    int wid = tid >> 6;
    int l16 = lane & 15;
    int kg = lane >> 4;

    f32x4 acc[4][4];
#pragma unroll
    for (int m = 0; m < 4; m++)
#pragma unroll
        for (int n = 0; n < 4; n++) acc[m][n] = (f32x4)(0.0f);

    const unsigned short* wp[4];
#pragma unroll
    for (int n = 0; n < 4; n++)
        wp[n] = Wt + (size_t)(wid * 64 + n * 16 + l16) * 256 + kg * 8;

#pragma unroll
    for (int c2 = 0; c2 < 8; c2++) {
        bf16x8 wfr[4];
#pragma unroll
        for (int n = 0; n < 4; n++) {
            BF8 t; t.u = *(const ushort8*)(wp[n] + c2 * 32);
            wfr[n] = t.b;
        }
        bf16x8 afr[4];
#pragma unroll
        for (int m = 0; m < 4; m++) {
            int row = m * 16 + l16;
            int cchunk = (c2 * 4 + kg) ^ (row & 7);
            BF8 t;
            t.u = *(const ushort8*)((const char*)As + row * 512 + (cchunk << 4));
            afr[m] = t.b;
        }
#pragma unroll
        for (int m = 0; m < 4; m++)
#pragma unroll
            for (int n = 0; n < 4; n++)
                acc[m][n] = __builtin_amdgcn_mfma_f32_16x16x32_bf16(wfr[n], afr[m], acc[m][n], 0, 0, 0);
    }

#pragma unroll
    for (int m = 0; m < 4; m++) {
        int node = rowbase + m * 16 + l16;
        if (node >= M) continue;
#pragma unroll
        for (int n = 0; n < 4; n++) {
            int col = wid * 64 + n * 16 + kg * 4;
            float4 bv = *(const float4*)(bias + col);
            float4 o;
            o.x = acc[m][n][0] + bv.x;
            o.y = acc[m][n][1] + bv.y;
            o.z = acc[m][n][2] + bv.z;
            o.w = acc[m][n][3] + bv.w;
            *(float4*)(C + (size_t)node * 256 + col) = o;
        }
    }
}

// ---------- scores in CSR order + per-head max partials ----------
__global__ __launch_bounds__(256) void score2_kernel(
    const unsigned short* __restrict__ qb, const unsigned short* __restrict__ kb,
    const int* __restrict__ src_s, const int* __restrict__ dst_s,
    const float* __restrict__ et_s, const float* __restrict__ node_time,
    const float* __restrict__ Wt, const float* __restrict__ bt,
    float* __restrict__ scores, unsigned* __restrict__ partialmax)
{
    __shared__ unsigned smax[8];
    int tid = threadIdx.x;
    if (tid < 8) smax[tid] = 0u;
    __syncthreads();
    const int total = NUM_EDGES * 8;
    int t0 = blockIdx.x * 256 + tid;
    int stride = gridDim.x * 256;
    int h = t0 & 7;
    float wt0 = Wt[h], wt1 = Wt[8 + h], btv = bt[h];
    unsigned mykey = 0u;
    for (int t = t0; t < total; t += stride) {
        int pos = t >> 3;
        int s = src_s[pos], d = dst_s[pos];
        const ushort8* qp = (const ushort8*)(qb + (size_t)d * 256 + h * 32);
        const ushort8* kp = (const ushort8*)(kb + (size_t)s * 256 + h * 32);
        float dotv = 0.f;
#pragma unroll
        for (int i = 0; i < 4; i++) {
            ushort8 a = qp[i], b = kp[i];
#pragma unroll
            for (int j = 0; j < 8; j++) dotv += bf2f(a[j]) * bf2f(b[j]);
        }
        float td = et_s[pos] - node_time[d];
        float tf0 = (td > 0.f) ? 1.f : ((td < 0.f) ? -1.f : 0.f);
        float tf1 = log1pf(fabsf(td) * (1.f / 3600.f));
        float sc = dotv * 0.17677669529663687f + (tf0 * wt0 + tf1 * wt1 + btv);
        scores[t] = sc;
        unsigned kkey = float_to_key(sc);
        mykey = (kkey > mykey) ? kkey : mykey;
    }
    atomicMax(&smax[h], mykey);
    __syncthreads();
    if (tid < 8) partialmax[blockIdx.x * 8 + tid] = smax[tid];
}

__global__ __launch_bounds__(256) void reduce_max_kernel(
    const unsigned* __restrict__ partialmax, float* __restrict__ headmax)
{
    int tid = threadIdx.x;
    int h = tid >> 5, lane = tid & 31;
    unsigned m = 0u;
    for (int i = lane; i < 1024; i += 32) {
        unsigned v = partialmax[i * 8 + h];
        m = (v > m) ? v : m;
    }
    for (int off = 16; off > 0; off >>= 1) {
        unsigned o = __shfl_down(m, off, 32);
        m = (o > m) ? o : m;
    }
    if (lane == 0) headmax[h] = key_to_float(m);
}

// ---------- fused exp + aggregate, exp staged in LDS once ----------
__global__ __launch_bounds__(256) void aggregate3_kernel(
    const unsigned short* __restrict__ vb, const float* __restrict__ scores,
    const int* __restrict__ src_s, const int* __restrict__ offs,
    const float* __restrict__ headmax, float* __restrict__ agg,
    float* __restrict__ psum_part)
{
    __shared__ int ssrc[64];
    __shared__ float pl[64 * 8];
    __shared__ float hm[8];
    int n = blockIdx.x;
    int tid = threadIdx.x;
    int h = tid >> 5;
    if (tid < 8) hm[tid] = headmax[tid];
    __syncthreads();
    int start = offs[n], end = offs[n + 1];
    float acc = 0.f;
    float psum = 0.f;
    for (int cb = start; cb < end; cb += 64) {
        int cnt = min(64, end - cb);
        __syncthreads();
        if (tid < cnt) ssrc[tid] = src_s[cb + tid];
        {
            int i0 = tid;
            int j0 = i0 >> 3;
            if (j0 < cnt) pl[i0] = __expf(scores[(size_t)(cb + j0) * 8 + (i0 & 7)] - hm[i0 & 7]);
            int i1 = tid + 256;
            int j1 = i1 >> 3;
            if (j1 < cnt) pl[i1] = __expf(scores[(size_t)(cb + j1) * 8 + (i1 & 7)] - hm[i1 & 7]);
        }
        __syncthreads();
        for (int j = 0; j < cnt; j++) {
            int s = ssrc[j];
            float p = pl[j * 8 + h];
            acc += p * bf2f(vb[(size_t)s * 256 + tid]);
            psum += p;
        }
    }
    agg[(size_t)n * 256 + tid] = acc;
    if ((tid & 31) == 0) psum_part[(size_t)n * 8 + h] = psum;
}

__global__ __launch_bounds__(256) void reduce_sum_stage1(
    const float* __restrict__ psum_part, float* __restrict__ partial2)
{
    __shared__ float ssum[8];
    int tid = threadIdx.x;
    if (tid < 8) ssum[tid] = 0.f;
    __syncthreads();
    const int total = NUM_NODES * 8;
    int t0 = blockIdx.x * 256 + tid;
    int stride = gridDim.x * 256;
    int h = t0 & 7;
    float s = 0.f;
    for (int t = t0; t < total; t += stride) s += psum_part[t];
    atomicAdd(&ssum[h], s);
    __syncthreads();
    if (tid < 8) partial2[blockIdx.x * 8 + tid] = ssum[tid];
}

__global__ __launch_bounds__(256) void reduce_sum_final(
    const float* __restrict__ partial2, float* __restrict__ headinv)
{
    int tid = threadIdx.x;
    int h = tid >> 5, lane = tid & 31;
    float s = 0.f;
    for (int i = lane; i < 256; i += 32) s += partial2[i * 8 + h];
    for (int off = 16; off > 0; off >>= 1) s += __shfl_down(s, off, 32);
    if (lane == 0) headinv[h] = 1.f / s;
}

extern "C" void kernel_launch(void* const* d_in, const int* in_sizes, int n_in,
                              void* d_out, int out_size, void* d_ws, size_t ws_size,
                              hipStream_t stream) {
    const float* x = (const float*)d_in[0];
    const int* ei = (const int*)d_in[1];
    const int* src_idx = ei;
    const int* dst_idx = ei + NUM_EDGES;
    const float* edge_time = (const float*)d_in[2];
    const float* node_time = (const float*)d_in[3];
    const float* Wq = (const float*)d_in[4];  const float* bq = (const float*)d_in[5];
    const float* Wk = (const float*)d_in[6];  const float* bk = (const float*)d_in[7];
    const float* Wv = (const float*)d_in[8];  const float* bv = (const float*)d_in[9];
    const float* Wt = (const float*)d_in[10]; const float* bt = (const float*)d_in[11];
    const float* Wo = (const float*)d_in[12]; const float* bo = (const float*)d_in[13];
    float* out = (float*)d_out;

    char* w = (char*)d_ws;
    unsigned short* qb = (unsigned short*)w; w += (size_t)NUM_NODES * 256 * 2;
    unsigned short* kb = (unsigned short*)w; w += (size_t)NUM_NODES * 256 * 2;
    unsigned short* vb = (unsigned short*)w; w += (size_t)NUM_NODES * 256 * 2;
    float* scores = (float*)w;      w += (size_t)NUM_EDGES * 8 * 4;
    float* agg = (float*)w;         w += (size_t)NUM_NODES * 256 * 4;
    int* src_s = (int*)w;           w += (size_t)NUM_EDGES * 4;
    int* dst_s = (int*)w;           w += (size_t)NUM_EDGES * 4;
    float* et_s = (float*)w;        w += (size_t)NUM_EDGES * 4;
    int* deg = (int*)w;             w += (size_t)NUM_NODES * 4;
    int* offs = (int*)w;            w += (size_t)(NUM_NODES + 1) * 4;
    int* cursor = (int*)w;          w += (size_t)NUM_NODES * 4;
    unsigned* partialmax = (unsigned*)w; w += 1024 * 8 * 4;
    float* psum_part = (float*)w;   w += (size_t)NUM_NODES * 8 * 4;
    float* partial2 = (float*)w;    w += 256 * 8 * 4;
    float* headmax = (float*)w;     w += 8 * 4;
    float* headinv = (float*)w;     w += 8 * 4;
    int* blocksum = (int*)w;        w += 64 * 4;
    int* bcarry = (int*)w;          w += 64 * 4;
    unsigned short* Wtb = (unsigned short*)w; w += (size_t)1024 * 256 * 2;

    hipMemsetAsync(deg, 0, (size_t)NUM_NODES * 4, stream);

    // weight transpose + bf16 cvt (q,k,v,o)
    dim3 gw(16, 4);
    wtrans_kernel<<<gw, 256, 0, stream>>>(Wq, Wk, Wv, Wo, Wtb);

    // CSR by dst (parallel scan)
    deg_kernel<<<(NUM_EDGES + 255) / 256, 256, 0, stream>>>(dst_idx, deg);
    scanA_kernel<<<SCAN_BLOCKS, 1024, 0, stream>>>(deg, offs, blocksum);
    scanB_kernel<<<1, 64, 0, stream>>>(blocksum, bcarry, offs);
    scanC_kernel<<<(NUM_NODES + 255) / 256, 256, 0, stream>>>(offs, bcarry, cursor);
    fill2_kernel<<<(NUM_EDGES + 255) / 256, 256, 0, stream>>>(src_idx, dst_idx, edge_time,
                                                              cursor, src_s, dst_s, et_s);

    // QKV projection -> bf16 q/k/v  (MFMA, 64-row tiles)
    gemm_qkv_mfma3<<<(NUM_NODES + 63) / 64, 256, 0, stream>>>(
        x, NUM_NODES, Wtb, bq, bk, bv, qb, kb, vb);

    // scores (CSR order) + per-head max
    score2_kernel<<<1024, 256, 0, stream>>>(qb, kb, src_s, dst_s, et_s, node_time,
                                            Wt, bt, scores, partialmax);
    reduce_max_kernel<<<1, 256, 0, stream>>>(partialmax, headmax);

    // fused exp + aggregate + per-head sum partials
    aggregate3_kernel<<<NUM_NODES, 256, 0, stream>>>(vb, scores, src_s, offs, headmax,
                                                     agg, psum_part);
    reduce_sum_stage1<<<256, 256, 0, stream>>>(psum_part, partial2);
    reduce_sum_final<<<1, 256, 0, stream>>>(partial2, headinv);

    // output projection with per-head 1/sum folded into A (MFMA, 64-row tiles)
    gemm_out_mfma3<<<(NUM_NODES + 63) / 64, 256, 0, stream>>>(
        agg, NUM_NODES, Wtb + (size_t)768 * 256, bo, headinv, out);
}